// Round 1
// 553.010 us; speedup vs baseline: 1.0071x; 1.0071x over previous
//
#include <hip/hip_runtime.h>
#include <math.h>

#define D 128
#define B2D 256
#define NSEG 64
#define MAXC 512
#define PSTRIDE 144   // floats per chunk-partial: [0]=m, [1]=s, [8..135]=acc[128]

// ---------------- init: zero LSTM state/q_star + segment offsets (eb sorted) ----------------
__global__ void k_init(const int* __restrict__ eb, int* __restrict__ seg_ofs,
                       float* __restrict__ zbuf, int E) {
    int i = blockIdx.x * blockDim.x + threadIdx.x;
    if (i < 32768) zbuf[i] = 0.f;           // h, c, q_star
    if (i >= E) return;
    int b = eb[i];
    if (i == 0) {
        for (int j = 0; j <= b; ++j) seg_ofs[j] = 0;
    } else {
        int p = eb[i - 1];
        if (p != b) for (int j = p + 1; j <= b; ++j) seg_ofs[j] = i;
    }
    if (i == E - 1) {
        for (int j = b + 1; j <= NSEG; ++j) seg_ofs[j] = E;
    }
}

// ---------------- per-segment chunking: chunk counts, prefix, edges-per-wave ----------------
__global__ void k_seginfo(const int* __restrict__ seg_ofs, int* __restrict__ pre,
                          int* __restrict__ epw) {
    __shared__ int cnt[NSEG];
    int b = threadIdx.x;
    if (b < NSEG) {
        int len = seg_ofs[b + 1] - seg_ofs[b];
        int e = 64;                           // multiple of 4: full chunks have no masked tail
        int c = (len + e - 1) / e;
        if (c > MAXC) { e = (len + MAXC - 1) / MAXC; c = (len + e - 1) / e; }
        if (len == 0) c = 0;
        epw[b] = e;
        cnt[b] = c;
    }
    __syncthreads();
    if (threadIdx.x == 0) {
        int acc = 0;
        for (int j = 0; j < NSEG; ++j) { pre[j] = acc; acc += cnt[j]; }
        pre[NSEG] = acc;
    }
}

// ---------------- LSTM cell: one block per batch row ----------------
__global__ __launch_bounds__(512) void k_lstm(
        const float* __restrict__ w_ih, const float* __restrict__ w_hh,
        const float* __restrict__ b_ih, const float* __restrict__ b_hh,
        float* __restrict__ h, float* __restrict__ c, float* __restrict__ q_star) {
    int b = blockIdx.x;   // 0..63
    int t = threadIdx.x;  // 0..511  (gate index, order i|f|g|o)
    __shared__ float s_x[B2D];
    __shared__ float s_h[D];
    __shared__ float s_g[4 * D];
    if (t < B2D) s_x[t] = q_star[b * B2D + t];
    else if (t < B2D + D) s_h[t - B2D] = h[b * D + (t - B2D)];
    __syncthreads();

    float acc = b_ih[t] + b_hh[t];
    const float* wr = w_ih + (size_t)t * B2D;
    #pragma unroll 8
    for (int k = 0; k < B2D; k += 4) {
        float4 w4 = *(const float4*)(wr + k);
        acc += w4.x * s_x[k] + w4.y * s_x[k + 1] + w4.z * s_x[k + 2] + w4.w * s_x[k + 3];
    }
    const float* wh = w_hh + (size_t)t * D;
    #pragma unroll 8
    for (int k = 0; k < D; k += 4) {
        float4 w4 = *(const float4*)(wh + k);
        acc += w4.x * s_h[k] + w4.y * s_h[k + 1] + w4.z * s_h[k + 2] + w4.w * s_h[k + 3];
    }
    s_g[t] = acc;
    __syncthreads();

    if (t < D) {
        float gi = s_g[t], gf = s_g[t + D], gg = s_g[t + 2 * D], go = s_g[t + 3 * D];
        float si = 1.f / (1.f + expf(-gi));
        float sf = 1.f / (1.f + expf(-gf));
        float so = 1.f / (1.f + expf(-go));
        float cn = sf * c[b * D + t] + si * tanhf(gg);
        float hn = so * tanhf(cn);
        c[b * D + t] = cn;
        h[b * D + t] = hn;
        q_star[b * B2D + t] = hn;            // q half
    }
}

// ---------------- fused single-pass: logits + online softmax + weighted accumulate ----------------
// One wave per chunk. 4 edges per wave-iteration (2 per half-wave), with the next
// group's loads issued before the current group's shuffle/update chain.
__global__ __launch_bounds__(256) void k_pass(
        const float* __restrict__ feat, const int* __restrict__ seg_ofs,
        const int* __restrict__ pre, const int* __restrict__ epw,
        const float* __restrict__ h, float* __restrict__ part) {
    __shared__ int s_pre[NSEG + 1], s_ofs[NSEG + 1], s_epw[NSEG];
    int tid = threadIdx.x;
    if (tid <= NSEG) { s_pre[tid] = pre[tid]; s_ofs[tid] = seg_ofs[tid]; }
    if (tid < NSEG) s_epw[tid] = epw[tid];
    __syncthreads();
    int total = s_pre[NSEG];
    int wave = (blockIdx.x * blockDim.x + tid) >> 6;
    int nwaves = (gridDim.x * blockDim.x) >> 6;
    int lane = tid & 63, half = lane >> 5, sl = lane & 31;

    for (int cid = wave; cid < total; cid += nwaves) {
        // binary search: largest b with s_pre[b] <= cid
        int lo = 0, hi = NSEG - 1;
        while (lo < hi) {
            int mid = (lo + hi + 1) >> 1;
            if (s_pre[mid] <= cid) lo = mid; else hi = mid - 1;
        }
        int b = lo;
        int chunk = cid - s_pre[b];
        int e = s_epw[b];
        long s0 = (long)s_ofs[b] + (long)chunk * e;
        long s1 = (long)s_ofs[b + 1];
        long send = s0 + e;
        if (send < s1) s1 = send;

        float4 q4 = *(const float4*)(h + (size_t)b * D + sl * 4);
        float m = -INFINITY, ssum = 0.f;
        float4 acc = make_float4(0.f, 0.f, 0.f, 0.f);

        long nfull = (s1 - s0) >> 2;          // 4-edge groups
        long ee = s0 + nfull * 4;

        if (nfull > 0) {
            const float* p0 = feat + (size_t)(s0 + half) * D + sl * 4;
            float4 fa = *(const float4*)p0;          // edges s0, s0+1
            float4 fb = *(const float4*)(p0 + 2 * D); // edges s0+2, s0+3
            for (long g = 0; g < nfull; ++g) {
                float4 ca = fa, cb = fb;
                if (g + 1 < nfull) {                  // prefetch next group
                    const float* pn = feat + (size_t)(s0 + (g + 1) * 4 + half) * D + sl * 4;
                    fa = *(const float4*)pn;
                    fb = *(const float4*)(pn + 2 * D);
                }
                float pa = ca.x * q4.x + ca.y * q4.y + ca.z * q4.z + ca.w * q4.w;
                float pb = cb.x * q4.x + cb.y * q4.y + cb.z * q4.z + cb.w * q4.w;
                pa += __shfl_xor(pa, 16, 32); pb += __shfl_xor(pb, 16, 32);
                pa += __shfl_xor(pa, 8, 32);  pb += __shfl_xor(pb, 8, 32);
                pa += __shfl_xor(pa, 4, 32);  pb += __shfl_xor(pb, 4, 32);
                pa += __shfl_xor(pa, 2, 32);  pb += __shfl_xor(pb, 2, 32);
                pa += __shfl_xor(pa, 1, 32);  pb += __shfl_xor(pb, 1, 32);
                float nm = fmaxf(m, fmaxf(pa, pb));
                float sc = __expf(m - nm);            // exp(-inf)=0 handles first group
                float wa = __expf(pa - nm);
                float wb = __expf(pb - nm);
                ssum = ssum * sc + wa + wb;
                acc.x = acc.x * sc + wa * ca.x + wb * cb.x;
                acc.y = acc.y * sc + wa * ca.y + wb * cb.y;
                acc.z = acc.z * sc + wa * ca.z + wb * cb.z;
                acc.w = acc.w * sc + wa * ca.w + wb * cb.w;
                m = nm;
            }
        }

        // tail: 0..3 edges, 2-wide masked
        for (; ee < s1; ee += 2) {
            long my_e = ee + half;
            bool valid = my_e < s1;
            float4 f4 = make_float4(0.f, 0.f, 0.f, 0.f);
            if (valid) f4 = *(const float4*)(feat + (size_t)my_e * D + sl * 4);
            float p = f4.x * q4.x + f4.y * q4.y + f4.z * q4.z + f4.w * q4.w;
            p += __shfl_xor(p, 16, 32);
            p += __shfl_xor(p, 8, 32);
            p += __shfl_xor(p, 4, 32);
            p += __shfl_xor(p, 2, 32);
            p += __shfl_xor(p, 1, 32);
            if (valid) {
                float nm = fmaxf(m, p);
                float sc = __expf(m - nm);
                float we = __expf(p - nm);
                ssum = ssum * sc + we;
                acc.x = acc.x * sc + we * f4.x;
                acc.y = acc.y * sc + we * f4.y;
                acc.z = acc.z * sc + we * f4.z;
                acc.w = acc.w * sc + we * f4.w;
                m = nm;
            }
        }

        // merge the two half-wave states
        float m_o = __shfl_xor(m, 32);
        float s_o = __shfl_xor(ssum, 32);
        float4 a_o;
        a_o.x = __shfl_xor(acc.x, 32);
        a_o.y = __shfl_xor(acc.y, 32);
        a_o.z = __shfl_xor(acc.z, 32);
        a_o.w = __shfl_xor(acc.w, 32);
        float nm = fmaxf(m, m_o);            // at least one half saw an edge
        float sa = __expf(m - nm), sb = __expf(m_o - nm);
        float sm = ssum * sa + s_o * sb;
        float4 am;
        am.x = acc.x * sa + a_o.x * sb;
        am.y = acc.y * sa + a_o.y * sb;
        am.z = acc.z * sa + a_o.z * sb;
        am.w = acc.w * sa + a_o.w * sb;

        float* dst = part + (size_t)cid * PSTRIDE;
        if (lane == 0) { dst[0] = nm; dst[1] = sm; }
        if (half == 0) *(float4*)(dst + 8 + sl * 4) = am;
    }
}

// ---------------- combine chunk partials per segment (no atomics) ----------------
__global__ __launch_bounds__(128) void k_combine(
        const float* __restrict__ part, const int* __restrict__ pre,
        float* __restrict__ q_star, float* __restrict__ out, int last) {
    int b = blockIdx.x, t = threadIdx.x;
    int c0 = pre[b], c1 = pre[b + 1];
    int nc = c1 - c0;
    __shared__ float s_w[MAXC];
    __shared__ float red[128];

    // pass 1: global max of chunk maxima
    float M = -INFINITY;
    for (int c = t; c < nc; c += 128) M = fmaxf(M, part[(size_t)(c0 + c) * PSTRIDE]);
    red[t] = M; __syncthreads();
    for (int o = 64; o > 0; o >>= 1) {
        if (t < o) red[t] = fmaxf(red[t], red[t + o]);
        __syncthreads();
    }
    M = red[0]; __syncthreads();

    // pass 2: per-chunk weights + rescaled sum
    float S = 0.f;
    for (int c = t; c < nc; c += 128) {
        const float* pe = part + (size_t)(c0 + c) * PSTRIDE;
        float w = __expf(pe[0] - M);
        s_w[c] = w;
        S += w * pe[1];
    }
    red[t] = S; __syncthreads();
    for (int o = 64; o > 0; o >>= 1) {
        if (t < o) red[t] += red[t + o];
        __syncthreads();
    }
    S = red[0]; __syncthreads();

    // pass 3: rescaled accumulator, one feature dim per thread
    float R = 0.f;
    for (int c = 0; c < nc; ++c)
        R += s_w[c] * part[(size_t)(c0 + c) * PSTRIDE + 8 + t];
    float r = R / (S + 1e-8f);
    q_star[b * B2D + D + t] = r;
    if (last) {                               // fold in the final copy
        out[b * B2D + D + t] = r;
        out[b * B2D + t] = q_star[b * B2D + t];  // q half (written by k_lstm this iter)
    }
}

extern "C" void kernel_launch(void* const* d_in, const int* in_sizes, int n_in,
                              void* d_out, int out_size, void* d_ws, size_t ws_size,
                              hipStream_t stream) {
    const float* feat = (const float*)d_in[0];
    const int*   eb   = (const int*)d_in[1];
    const float* w_ih = (const float*)d_in[2];
    const float* w_hh = (const float*)d_in[3];
    const float* b_ih = (const float*)d_in[4];
    const float* b_hh = (const float*)d_in[5];
    float* out = (float*)d_out;
    float* ws  = (float*)d_ws;
    const int E = in_sizes[1];   // 500000

    // workspace layout (float offsets)
    float* h      = ws;                  // 64*128
    float* c      = ws + 8192;           // 64*128
    float* q_star = ws + 16384;          // 64*256
    int*   seg    = (int*)(ws + 32768);  // 65
    int*   pre    = (int*)(ws + 32840);  // 65
    int*   epw    = (int*)(ws + 32912);  // 64
    float* part   = ws + 33024;          // up to 64*512*144 floats (~19 MB)

    // zero LSTM state + segment offsets (input is sorted), then chunk mapping
    k_init<<<(E + 255) / 256, 256, 0, stream>>>(eb, seg, ws, E);
    k_seginfo<<<1, 64, 0, stream>>>(seg, pre, epw);

    const int BLOCKS = 2048, THREADS = 256;  // 8192 waves, full device residency
    for (int it = 0; it < 3; ++it) {
        k_lstm<<<NSEG, 512, 0, stream>>>(w_ih, w_hh, b_ih, b_hh, h, c, q_star);
        k_pass<<<BLOCKS, THREADS, 0, stream>>>(feat, seg, pre, epw, h, part);
        k_combine<<<NSEG, 128, 0, stream>>>(part, pre, q_star, out, it == 2);
    }
}

// Round 2
// 531.276 us; speedup vs baseline: 1.0483x; 1.0409x over previous
//
#include <hip/hip_runtime.h>
#include <math.h>

#define D 128
#define B2D 256
#define NSEG 64
#define MAXC 512
#define PSTRIDE 144   // floats per chunk-partial: [0]=m, [1]=s, [8..135]=acc[128]

// ---------------- segment offsets (edge_batch is sorted) ----------------
__global__ void k_init(const int* __restrict__ eb, int* __restrict__ seg_ofs, int E) {
    int i = blockIdx.x * blockDim.x + threadIdx.x;
    if (i >= E) return;
    int b = eb[i];
    if (i == 0) {
        for (int j = 0; j <= b; ++j) seg_ofs[j] = 0;
    } else {
        int p = eb[i - 1];
        if (p != b) for (int j = p + 1; j <= b; ++j) seg_ofs[j] = i;
    }
    if (i == E - 1) {
        for (int j = b + 1; j <= NSEG; ++j) seg_ofs[j] = E;
    }
}

// ---------------- chunk mapping + closed-form first LSTM step ----------------
// Iteration 1 has q_star=0, h=0, c=0  =>  gates = b_ih+b_hh (identical for all
// 64 rows): h1/c1 computed here with no weight reads; no state zeroing needed.
__global__ __launch_bounds__(128) void k_seginfo(
        const int* __restrict__ seg_ofs, int* __restrict__ pre, int* __restrict__ epw,
        const float* __restrict__ b_ih, const float* __restrict__ b_hh,
        float* __restrict__ h, float* __restrict__ c) {
    __shared__ int cnt[NSEG];
    int t = threadIdx.x;   // 0..127
    if (t < NSEG) {
        int len = seg_ofs[t + 1] - seg_ofs[t];
        int e = 64;                           // multiple of 4: full chunks have no tail
        int cc = (len + e - 1) / e;
        if (cc > MAXC) { e = (len + MAXC - 1) / MAXC; cc = (len + e - 1) / e; }
        if (len == 0) cc = 0;
        epw[t] = e;
        cnt[t] = cc;
    }
    __syncthreads();
    if (t == 0) {
        int acc = 0;
        for (int j = 0; j < NSEG; ++j) { pre[j] = acc; acc += cnt[j]; }
        pre[NSEG] = acc;
    }
    // closed-form LSTM step 1 (per feature dim t)
    float gi = b_ih[t] + b_hh[t];
    float gg = b_ih[t + 2 * D] + b_hh[t + 2 * D];
    float go = b_ih[t + 3 * D] + b_hh[t + 3 * D];
    float si = 1.f / (1.f + expf(-gi));
    float so = 1.f / (1.f + expf(-go));
    float cn = si * tanhf(gg);               // sigmoid(f)*c0 term drops (c0=0)
    float hn = so * tanhf(cn);
    for (int b = 0; b < NSEG; ++b) { h[b * D + t] = hn; c[b * D + t] = cn; }
}

// ---------------- fused single-pass: logits + online softmax + weighted accumulate ----------------
// One wave per chunk; 4 edges per wave-iteration (2 per half-wave), next group
// prefetched before the current group's shuffle/update chain. BW-bound.
__global__ __launch_bounds__(256) void k_pass(
        const float* __restrict__ feat, const int* __restrict__ seg_ofs,
        const int* __restrict__ pre, const int* __restrict__ epw,
        const float* __restrict__ h, float* __restrict__ part) {
    __shared__ int s_pre[NSEG + 1], s_ofs[NSEG + 1], s_epw[NSEG];
    int tid = threadIdx.x;
    if (tid <= NSEG) { s_pre[tid] = pre[tid]; s_ofs[tid] = seg_ofs[tid]; }
    if (tid < NSEG) s_epw[tid] = epw[tid];
    __syncthreads();
    int total = s_pre[NSEG];
    int wave = (blockIdx.x * blockDim.x + tid) >> 6;
    int nwaves = (gridDim.x * blockDim.x) >> 6;
    int lane = tid & 63, half = lane >> 5, sl = lane & 31;

    for (int cid = wave; cid < total; cid += nwaves) {
        // binary search: largest b with s_pre[b] <= cid
        int lo = 0, hi = NSEG - 1;
        while (lo < hi) {
            int mid = (lo + hi + 1) >> 1;
            if (s_pre[mid] <= cid) lo = mid; else hi = mid - 1;
        }
        int b = lo;
        int chunk = cid - s_pre[b];
        int e = s_epw[b];
        long s0 = (long)s_ofs[b] + (long)chunk * e;
        long s1 = (long)s_ofs[b + 1];
        long send = s0 + e;
        if (send < s1) s1 = send;

        float4 q4 = *(const float4*)(h + (size_t)b * D + sl * 4);
        float m = -INFINITY, ssum = 0.f;
        float4 acc = make_float4(0.f, 0.f, 0.f, 0.f);

        long nfull = (s1 - s0) >> 2;          // 4-edge groups
        long ee = s0 + nfull * 4;

        if (nfull > 0) {
            const float* p = feat + (size_t)(s0 + half) * D + sl * 4;
            float4 fa = *(const float4*)p;           // edges s0, s0+1
            float4 fb = *(const float4*)(p + 2 * D); // edges s0+2, s0+3
            p += 4 * D;
            #pragma unroll 2
            for (long g = 0; g < nfull; ++g) {
                float4 ca = fa, cb = fb;
                if (g + 1 < nfull) {                  // prefetch next group
                    fa = *(const float4*)p;
                    fb = *(const float4*)(p + 2 * D);
                    p += 4 * D;
                }
                float pa = ca.x * q4.x + ca.y * q4.y + ca.z * q4.z + ca.w * q4.w;
                float pb = cb.x * q4.x + cb.y * q4.y + cb.z * q4.z + cb.w * q4.w;
                pa += __shfl_xor(pa, 16, 32); pb += __shfl_xor(pb, 16, 32);
                pa += __shfl_xor(pa, 8, 32);  pb += __shfl_xor(pb, 8, 32);
                pa += __shfl_xor(pa, 4, 32);  pb += __shfl_xor(pb, 4, 32);
                pa += __shfl_xor(pa, 2, 32);  pb += __shfl_xor(pb, 2, 32);
                pa += __shfl_xor(pa, 1, 32);  pb += __shfl_xor(pb, 1, 32);
                float nm = fmaxf(m, fmaxf(pa, pb));
                float sc = __expf(m - nm);            // exp(-inf)=0 handles first group
                float wa = __expf(pa - nm);
                float wb = __expf(pb - nm);
                ssum = ssum * sc + wa + wb;
                acc.x = acc.x * sc + wa * ca.x + wb * cb.x;
                acc.y = acc.y * sc + wa * ca.y + wb * cb.y;
                acc.z = acc.z * sc + wa * ca.z + wb * cb.z;
                acc.w = acc.w * sc + wa * ca.w + wb * cb.w;
                m = nm;
            }
        }

        // tail: 0..3 edges, 2-wide masked
        for (; ee < s1; ee += 2) {
            long my_e = ee + half;
            bool valid = my_e < s1;
            float4 f4 = make_float4(0.f, 0.f, 0.f, 0.f);
            if (valid) f4 = *(const float4*)(feat + (size_t)my_e * D + sl * 4);
            float p = f4.x * q4.x + f4.y * q4.y + f4.z * q4.z + f4.w * q4.w;
            p += __shfl_xor(p, 16, 32);
            p += __shfl_xor(p, 8, 32);
            p += __shfl_xor(p, 4, 32);
            p += __shfl_xor(p, 2, 32);
            p += __shfl_xor(p, 1, 32);
            if (valid) {
                float nm = fmaxf(m, p);
                float sc = __expf(m - nm);
                float we = __expf(p - nm);
                ssum = ssum * sc + we;
                acc.x = acc.x * sc + we * f4.x;
                acc.y = acc.y * sc + we * f4.y;
                acc.z = acc.z * sc + we * f4.z;
                acc.w = acc.w * sc + we * f4.w;
                m = nm;
            }
        }

        // merge the two half-wave states
        float m_o = __shfl_xor(m, 32);
        float s_o = __shfl_xor(ssum, 32);
        float4 a_o;
        a_o.x = __shfl_xor(acc.x, 32);
        a_o.y = __shfl_xor(acc.y, 32);
        a_o.z = __shfl_xor(acc.z, 32);
        a_o.w = __shfl_xor(acc.w, 32);
        float nm = fmaxf(m, m_o);
        float sa = __expf(m - nm), sb = __expf(m_o - nm);
        float sm = ssum * sa + s_o * sb;
        float4 am;
        am.x = acc.x * sa + a_o.x * sb;
        am.y = acc.y * sa + a_o.y * sb;
        am.z = acc.z * sa + a_o.z * sb;
        am.w = acc.w * sa + a_o.w * sb;

        float* dst = part + (size_t)cid * PSTRIDE;
        if (lane == 0) { dst[0] = nm; dst[1] = sm; }
        if (half == 0) *(float4*)(dst + 8 + sl * 4) = am;
    }
}

// ---------------- fused: combine chunk partials + next-iteration LSTM cell ----------------
// Block b owns segment/row b. Readout stays in smem; q_star never hits global.
// last=1: write final output instead of running the LSTM.
__global__ __launch_bounds__(512) void k_comb_lstm(
        const float* __restrict__ part, const int* __restrict__ pre,
        const float* __restrict__ w_ih, const float* __restrict__ w_hh,
        const float* __restrict__ b_ih, const float* __restrict__ b_hh,
        float* __restrict__ h, float* __restrict__ c,
        float* __restrict__ out, int last) {
    int b = blockIdx.x, t = threadIdx.x;   // t: 0..511
    int c0 = pre[b], nc = pre[b + 1] - c0;
    __shared__ float s_w[MAXC];
    __shared__ float red[512];
    __shared__ float s_r[D];    // readout
    __shared__ float s_h[D];    // h_prev (== q)
    __shared__ float s_g[4 * D];

    // pass 1: global max of chunk maxima
    float M = -INFINITY;
    for (int cc = t; cc < nc; cc += 512) M = fmaxf(M, part[(size_t)(c0 + cc) * PSTRIDE]);
    red[t] = M; __syncthreads();
    for (int o = 256; o > 0; o >>= 1) {
        if (t < o) red[t] = fmaxf(red[t], red[t + o]);
        __syncthreads();
    }
    M = red[0]; __syncthreads();

    // pass 2: per-chunk weights + rescaled sum
    float S = 0.f;
    for (int cc = t; cc < nc; cc += 512) {
        const float* pe = part + (size_t)(c0 + cc) * PSTRIDE;
        float w = __expf(pe[0] - M);
        s_w[cc] = w;
        S += w * pe[1];
    }
    red[t] = S; __syncthreads();
    for (int o = 256; o > 0; o >>= 1) {
        if (t < o) red[t] += red[t + o];
        __syncthreads();
    }
    S = red[0]; __syncthreads();

    // pass 3: rescaled accumulator; 4 thread-groups split the chunk loop
    int d = t & (D - 1), j = t >> 7;
    float R = 0.f;
    for (int cc = j; cc < nc; cc += 4)
        R += s_w[cc] * part[(size_t)(c0 + cc) * PSTRIDE + 8 + d];
    red[t] = R; __syncthreads();
    if (t < 256) red[t] += red[t + 256];
    __syncthreads();
    if (t < D) {
        float r = (red[t] + red[t + 128]) / (S + 1e-8f);
        s_r[t] = r;
        s_h[t] = h[b * D + t];
        if (last) { out[b * B2D + D + t] = r; out[b * B2D + t] = s_h[t]; }
    }
    __syncthreads();
    if (last) return;

    // LSTM cell for the next iteration: x = [h_prev, readout], h = h_prev
    float acc = b_ih[t] + b_hh[t];
    const float* wr = w_ih + (size_t)t * B2D;
    #pragma unroll 8
    for (int k = 0; k < D; k += 4) {
        float4 w4 = *(const float4*)(wr + k);
        acc += w4.x * s_h[k] + w4.y * s_h[k + 1] + w4.z * s_h[k + 2] + w4.w * s_h[k + 3];
    }
    #pragma unroll 8
    for (int k = 0; k < D; k += 4) {
        float4 w4 = *(const float4*)(wr + D + k);
        acc += w4.x * s_r[k] + w4.y * s_r[k + 1] + w4.z * s_r[k + 2] + w4.w * s_r[k + 3];
    }
    const float* wh = w_hh + (size_t)t * D;
    #pragma unroll 8
    for (int k = 0; k < D; k += 4) {
        float4 w4 = *(const float4*)(wh + k);
        acc += w4.x * s_h[k] + w4.y * s_h[k + 1] + w4.z * s_h[k + 2] + w4.w * s_h[k + 3];
    }
    s_g[t] = acc;
    __syncthreads();

    if (t < D) {
        float gi = s_g[t], gf = s_g[t + D], gg = s_g[t + 2 * D], go = s_g[t + 3 * D];
        float si = 1.f / (1.f + expf(-gi));
        float sf = 1.f / (1.f + expf(-gf));
        float so = 1.f / (1.f + expf(-go));
        float cn = sf * c[b * D + t] + si * tanhf(gg);
        float hn = so * tanhf(cn);
        c[b * D + t] = cn;
        h[b * D + t] = hn;
    }
}

extern "C" void kernel_launch(void* const* d_in, const int* in_sizes, int n_in,
                              void* d_out, int out_size, void* d_ws, size_t ws_size,
                              hipStream_t stream) {
    const float* feat = (const float*)d_in[0];
    const int*   eb   = (const int*)d_in[1];
    const float* w_ih = (const float*)d_in[2];
    const float* w_hh = (const float*)d_in[3];
    const float* b_ih = (const float*)d_in[4];
    const float* b_hh = (const float*)d_in[5];
    float* out = (float*)d_out;
    float* ws  = (float*)d_ws;
    const int E = in_sizes[1];   // 500000

    // workspace layout (float offsets)
    float* h    = ws;                    // 64*128
    float* c    = ws + 8192;             // 64*128
    int*   seg  = (int*)(ws + 16384);    // 65
    int*   pre  = (int*)(ws + 16512);    // 65
    int*   epw  = (int*)(ws + 16640);    // 64
    float* part = ws + 16768;            // up to 64*512*144 floats (~19 MB)

    k_init<<<(E + 255) / 256, 256, 0, stream>>>(eb, seg, E);
    k_seginfo<<<1, 128, 0, stream>>>(seg, pre, epw, b_ih, b_hh, h, c);

    const int BLOCKS = 2048, THREADS = 256;  // 8192 waves
    for (int it = 0; it < 3; ++it) {
        k_pass<<<BLOCKS, THREADS, 0, stream>>>(feat, seg, pre, epw, h, part);
        k_comb_lstm<<<NSEG, 512, 0, stream>>>(part, pre, w_ih, w_hh, b_ih, b_hh,
                                              h, c, out, it == 2);
    }
}